// Round 6
// baseline (100.221 us; speedup 1.0000x reference)
//
#include <hip/hip_runtime.h>
#include <math.h>

#define DIMC 768
#define BATCH 16
#define HWSZ 1024
#define NT 32
#define SCH 16          // channel splits
#define CHPB 48         // channels per block

// out layout: result [16*32*768] | p [16*32*768] | mask [16*32*1024]
#define OUT_P_OFF    393216
#define OUT_MASK_OFF 786432

// ws layout (floats): partials [16][16][32][1024] | wt [768*32] | pk [768*12]
#define WS_WT_OFF 8388608
#define WS_PK_OFF 8413184

typedef float v4f __attribute__((ext_vector_type(4)));

// ---------------- K0: transpose pww -> wt[c][t]; pack per-channel params ---
// pk[c][12] = { dw[0..8], dw_bias, bn_scale, bn_shift }  (16B-aligned rows)
__global__ __launch_bounds__(256) void k0_prep(
    const float* __restrict__ pww,
    const float* __restrict__ dww, const float* __restrict__ dwb,
    const float* __restrict__ bnw, const float* __restrict__ bnb,
    const float* __restrict__ bnm, const float* __restrict__ bnv,
    float* __restrict__ wt, float* __restrict__ pk)
{
    int i = blockIdx.x * 256 + threadIdx.x;
    if (blockIdx.x < 96) {
        wt[i] = pww[(i & 31) * DIMC + (i >> 5)];
    } else {
        int c = i - 24576;
        if (c < DIMC) {
            float* o = pk + c * 12;
#pragma unroll
            for (int j = 0; j < 9; ++j) o[j] = dww[c * 9 + j];
            o[9] = dwb[c];
            float scale = bnw[c] * rsqrtf(bnv[c] + 1e-5f);
            o[10] = scale;
            o[11] = bnb[c] - bnm[c] * scale;
        }
    }
}

// ---------------- KF: fused BN + dw3x3 + hardswish + pointwise partials ----
// grid (pos-chunk=4, ch-chunk=16, b=16) = 1024 blocks x 512 threads.
// Lanes 0-255: tokens 0-15 of position tid; lanes 256-511: tokens 16-31.
// One channel per barrier-iter; everything prefetched one channel ahead.
__global__ __launch_bounds__(512) void kf_fused(
    const float* __restrict__ x,
    const float* __restrict__ wt, const float* __restrict__ pk,
    float* __restrict__ partials)
{
    const int b    = blockIdx.z;
    const int scc  = blockIdx.y;
    const int cb0  = scc * CHPB;
    const int r0   = blockIdx.x * 8;          // first output row
    const int tid  = threadIdx.x;
    const int pos  = tid & 255;
    const int rl   = pos >> 5;
    const int col  = pos & 31;
    const int tok0 = (tid >> 8) << 4;         // 0 or 16

    __shared__ float st[2][340];              // zero-padded 10x34 halo tiles
    for (int i = tid; i < 680; i += 512) ((float*)st)[i] = 0.0f;

    // one staging slot per thread (340 slots)
    const int sr = tid / 34, sc = tid - sr * 34;
    const int rr = r0 - 1 + sr, cc = sc - 1;
    const bool sval = (tid < 340) && rr >= 0 && rr < 32 && cc >= 0 && cc < 32;
    const int  soff = rr * 32 + cc;

    const float* xb  = x  + (size_t)(b * DIMC + cb0) * HWSZ;
    const float* pkb = pk + (size_t)cb0 * 12;
    const float* wtb = wt + (size_t)cb0 * NT + tok0;

    // prologue: params + weights + staged tile for channel 0
    v4f P0 = *(const v4f*)(pkb + 0);
    v4f P1 = *(const v4f*)(pkb + 4);
    v4f P2 = *(const v4f*)(pkb + 8);          // {w8, dwb, scale, shift}
    v4f W0 = *(const v4f*)(wtb + 0);
    v4f W1 = *(const v4f*)(wtb + 4);
    v4f W2 = *(const v4f*)(wtb + 8);
    v4f W3 = *(const v4f*)(wtb + 12);
    {
        float g = sval ? xb[soff] : 0.0f;
        if (sval) st[0][tid] = fmaf(g, P2.z, P2.w);
    }
    __syncthreads();

    v4f A0 = {0,0,0,0}, A1 = {0,0,0,0}, A2 = {0,0,0,0}, A3 = {0,0,0,0};
    const int base = rl * 34 + col;

    for (int k = 0; k < CHPB; ++k) {
        const float* S = &st[k & 1][0];

        // prefetch channel k+1: x tile slot, params, pw weights
        float g = 0.0f;
        v4f NP0, NP1, NP2, N0, N1, N2, N3;
        if (k < CHPB - 1) {
            const float* pn = pkb + (k + 1) * 12;
            NP0 = *(const v4f*)(pn + 0);
            NP1 = *(const v4f*)(pn + 4);
            NP2 = *(const v4f*)(pn + 8);
            const float* wn = wtb + (k + 1) * NT;
            N0 = *(const v4f*)(wn + 0);
            N1 = *(const v4f*)(wn + 4);
            N2 = *(const v4f*)(wn + 8);
            N3 = *(const v4f*)(wn + 12);
            if (sval) g = xb[(size_t)(k + 1) * HWSZ + soff];
        }

        // depthwise 3x3 + hardswish (current channel, prefetched params)
        float r = P2.y;
        r = fmaf(P0.x, S[base +  0], r);
        r = fmaf(P0.y, S[base +  1], r);
        r = fmaf(P0.z, S[base +  2], r);
        r = fmaf(P0.w, S[base + 34], r);
        r = fmaf(P1.x, S[base + 35], r);
        r = fmaf(P1.y, S[base + 36], r);
        r = fmaf(P1.z, S[base + 68], r);
        r = fmaf(P1.w, S[base + 69], r);
        r = fmaf(P2.x, S[base + 70], r);
        float clp = fminf(fmaxf(r + 3.0f, 0.0f), 6.0f);
        float hs  = r * clp * (1.0f / 6.0f);

        // pointwise: 16 tokens via packed-fma vectors
        v4f hsv = {hs, hs, hs, hs};
        A0 = __builtin_elementwise_fma(hsv, W0, A0);
        A1 = __builtin_elementwise_fma(hsv, W1, A1);
        A2 = __builtin_elementwise_fma(hsv, W2, A2);
        A3 = __builtin_elementwise_fma(hsv, W3, A3);

        // late BN + LDS write for k+1; rotate prefetched regs
        if (k < CHPB - 1) {
            if (sval) st[(k & 1) ^ 1][tid] = fmaf(g, NP2.z, NP2.w);
            P0 = NP0; P1 = NP1; P2 = NP2;
            W0 = N0;  W1 = N1;  W2 = N2;  W3 = N3;
        }
        __syncthreads();
    }

    // epilogue: 16 token-partials, coalesced per token across the wave
    float* po = partials + (((size_t)(scc * BATCH + b)) * NT + tok0) * HWSZ
              + blockIdx.x * 256 + pos;
    po[ 0 << 10] = A0.x; po[ 1 << 10] = A0.y; po[ 2 << 10] = A0.z; po[ 3 << 10] = A0.w;
    po[ 4 << 10] = A1.x; po[ 5 << 10] = A1.y; po[ 6 << 10] = A1.z; po[ 7 << 10] = A1.w;
    po[ 8 << 10] = A2.x; po[ 9 << 10] = A2.y; po[10 << 10] = A2.z; po[11 << 10] = A2.w;
    po[12 << 10] = A3.x; po[13 << 10] = A3.y; po[14 << 10] = A3.z; po[15 << 10] = A3.w;
}

// ---------------- K3: sum partials -> argmax mask -> gather-sum ------------
__global__ __launch_bounds__(256) void k3_mask_gather(
    const float* __restrict__ partials,
    const float* __restrict__ x, const float* __restrict__ posin,
    const float* __restrict__ bnw, const float* __restrict__ bnb,
    const float* __restrict__ bnm, const float* __restrict__ bnv,
    float* __restrict__ out)
{
    int bt = blockIdx.x;           // b*32 + t
    int b  = bt >> 5;
    int t  = bt & 31;
    int tid = threadIdx.x;

    const float4* pp4 = (const float4*)(partials + ((size_t)(b * NT) + t) * HWSZ) + tid;
    float4 acc = make_float4(0.f, 0.f, 0.f, 0.f);
#pragma unroll
    for (int s = 0; s < SCH; ++s) {
        float4 u = pp4[(size_t)s * (BATCH * NT * HWSZ / 4)];
        acc.x += u.x; acc.y += u.y; acc.z += u.z; acc.w += u.w;
    }

    float m = fmaxf(fmaxf(acc.x, acc.y), fmaxf(acc.z, acc.w));
#pragma unroll
    for (int off = 32; off; off >>= 1)
        m = fmaxf(m, __shfl_xor(m, off));
    __shared__ float wm[4];
    if ((tid & 63) == 0) wm[tid >> 6] = m;
    __syncthreads();
    m = fmaxf(fmaxf(wm[0], wm[1]), fmaxf(wm[2], wm[3]));

    __shared__ int nmatch;
    __shared__ int matchpos[16];
    if (tid == 0) nmatch = 0;
    __syncthreads();

    float* maskp = out + OUT_MASK_OFF + (size_t)bt * HWSZ;
    float4 mask4;
    const float* av = &acc.x;
    float* mv = &mask4.x;
#pragma unroll
    for (int j = 0; j < 4; ++j) {
        int hit = (av[j] == m);
        mv[j] = hit ? 1.0f : 0.0f;
        if (hit) {
            int k = atomicAdd(&nmatch, 1);
            if (k < 16) matchpos[k] = 4 * tid + j;
        }
    }
    ((float4*)maskp)[tid] = mask4;
    __syncthreads();
    int nm = nmatch < 16 ? nmatch : 16;

    const float* xb = x + (size_t)b * DIMC * HWSZ;
    const float* pb = posin + (size_t)b * DIMC * HWSZ;
    for (int c = tid; c < DIMC; c += 256) {
        float scale = bnw[c] * rsqrtf(bnv[c] + 1e-5f);
        float shift = bnb[c] - bnm[c] * scale;
        float rf = 0.0f, rp = 0.0f;
        for (int k = 0; k < nm; ++k) {
            int pos = matchpos[k];
            rf += xb[(size_t)c * HWSZ + pos] * scale + shift;
            rp += pb[(size_t)c * HWSZ + pos];
        }
        out[(size_t)bt * DIMC + c] = rf;
        out[OUT_P_OFF + (size_t)bt * DIMC + c] = rp;
    }
}

extern "C" void kernel_launch(void* const* d_in, const int* in_sizes, int n_in,
                              void* d_out, int out_size, void* d_ws, size_t ws_size,
                              hipStream_t stream)
{
    const float* x    = (const float*)d_in[0];
    const float* pos  = (const float*)d_in[1];
    const float* bnw  = (const float*)d_in[2];
    const float* bnb  = (const float*)d_in[3];
    const float* bnm  = (const float*)d_in[4];
    const float* bnv  = (const float*)d_in[5];
    const float* dww  = (const float*)d_in[6];
    const float* dwb  = (const float*)d_in[7];
    const float* pww  = (const float*)d_in[8];
    // d_in[9] (pw_bias) unused: constant per (b,t) row -> outputs invariant.
    float* out = (float*)d_out;

    float* partials = (float*)d_ws;
    float* wt       = (float*)d_ws + WS_WT_OFF;
    float* pk       = (float*)d_ws + WS_PK_OFF;

    k0_prep<<<99, 256, 0, stream>>>(pww, dww, dwb, bnw, bnb, bnm, bnv, wt, pk);
    kf_fused<<<dim3(4, SCH, BATCH), 512, 0, stream>>>(x, wt, pk, partials);
    k3_mask_gather<<<BATCH * NT, 256, 0, stream>>>(partials, x, pos,
                                                   bnw, bnb, bnm, bnv, out);
}

// Round 7
// 62.334 us; speedup vs baseline: 1.6078x; 1.6078x over previous
//
#include <hip/hip_runtime.h>
#include <math.h>

#define DIMC 768
#define BATCH 16
#define HWSZ 1024
#define NT 32

// out layout: result [16*32*768] | p [16*32*768] | mask [16*32*1024]
#define OUT_P_OFF    393216
#define OUT_MASK_OFF 786432

typedef float v4f __attribute__((ext_vector_type(4)));

// ---------------- K0: transpose pww -> wt[c][t]; pack per-channel params ---
// pk[c][12] = { dw[0..8], dw_bias, bn_scale, bn_shift } (48B rows, 16B-aligned)
__global__ __launch_bounds__(256) void k0_prep(
    const float* __restrict__ pww,
    const float* __restrict__ dww, const float* __restrict__ dwb,
    const float* __restrict__ bnw, const float* __restrict__ bnb,
    const float* __restrict__ bnm, const float* __restrict__ bnv,
    float* __restrict__ wt, float* __restrict__ pk)
{
    int i = blockIdx.x * 256 + threadIdx.x;
    if (i < 24576) wt[i] = pww[(i & 31) * DIMC + (i >> 5)];
    int c = i - 24576;
    if (c >= 0 && c < DIMC) {
        float* o = pk + c * 12;
#pragma unroll
        for (int j = 0; j < 9; ++j) o[j] = dww[c * 9 + j];
        o[9] = dwb[c];
        float scale = bnw[c] * rsqrtf(bnv[c] + 1e-5f);
        o[10] = scale;
        o[11] = bnb[c] - bnm[c] * scale;
    }
}

// ---------------- KF: fused BN + dw3x3 + hardswish + pointwise partials ----
// round-4 skeleton: 256 thr, one position/lane, one channel per barrier-iter.
// NEW: depth-3 register prefetch of x; SCH templated (32 when ws allows).
template<int CHPB>
__global__ __launch_bounds__(256) void kf_fused(
    const float* __restrict__ x,
    const float* __restrict__ wt, const float* __restrict__ pk,
    float* __restrict__ partials)
{
    const int b   = blockIdx.z;
    const int scc = blockIdx.y;
    const int cb0 = scc * CHPB;
    const int r0  = blockIdx.x * 8;           // first output row
    const int tid = threadIdx.x;
    const int rl  = tid >> 5;
    const int col = tid & 31;

    __shared__ float st[2][340];              // zero-padded 10x34 halo tiles
    for (int i = tid; i < 680; i += 256) ((float*)st)[i] = 0.0f;

    // staging geometry: slots tid and tid+256 over [10][34]
    const int i1  = tid + 256;
    const int sr0 = tid / 34, sc0 = tid - sr0 * 34;
    const int sr1 = i1 / 34,  sc1 = i1 - sr1 * 34;
    const int rr0 = r0 - 1 + sr0, cl0 = sc0 - 1;
    const int rr1 = r0 - 1 + sr1, cl1 = sc1 - 1;
    const bool va = rr0 >= 0 && rr0 < 32 && cl0 >= 0 && cl0 < 32;
    const bool vb = (i1 < 340) && rr1 >= 0 && rr1 < 32 && cl1 >= 0 && cl1 < 32;
    const int  oa = rr0 * 32 + cl0, ob = rr1 * 32 + cl1;

    const float* xb  = x  + (size_t)(b * DIMC + cb0) * HWSZ;
    const float* pkb = pk + (size_t)cb0 * 12;
    const float* wtb = wt + (size_t)cb0 * NT;

    // prologue: stage ch0 to LDS; issue ch1, ch2 into registers
    {
        float sc = pkb[10], sh = pkb[11];
        if (va) st[0][tid] = fmaf(xb[oa], sc, sh);
        if (vb) st[0][i1]  = fmaf(xb[ob], sc, sh);
    }
    float g1a = 0.f, g1b = 0.f, g2a = 0.f, g2b = 0.f;
    if (va) g1a = xb[(size_t)1 * HWSZ + oa];
    if (vb) g1b = xb[(size_t)1 * HWSZ + ob];
    if (va) g2a = xb[(size_t)2 * HWSZ + oa];
    if (vb) g2b = xb[(size_t)2 * HWSZ + ob];
    __syncthreads();

    v4f A0 = {0,0,0,0}, A1 = {0,0,0,0}, A2 = {0,0,0,0}, A3 = {0,0,0,0};
    v4f A4 = {0,0,0,0}, A5 = {0,0,0,0}, A6 = {0,0,0,0}, A7 = {0,0,0,0};
    const int base = rl * 34 + col;

    for (int k = 0; k < CHPB; ++k) {
        const float* S = &st[k & 1][base];

        // issue loads for channel k+3 (consumed 2 barriers later)
        float g3a = 0.f, g3b = 0.f;
        if (k + 3 < CHPB) {
            if (va) g3a = xb[(size_t)(k + 3) * HWSZ + oa];
            if (vb) g3b = xb[(size_t)(k + 3) * HWSZ + ob];
        }

        // depthwise 3x3 + hardswish (params via uniform s_load)
        const float* pr = pkb + k * 12;
        v4f P0 = *(const v4f*)(pr + 0);
        v4f P1 = *(const v4f*)(pr + 4);
        v4f P2 = *(const v4f*)(pr + 8);       // {w8, dwb, scale, shift}
        float r = P2.y;
        r = fmaf(P0.x, S[ 0], r);
        r = fmaf(P0.y, S[ 1], r);
        r = fmaf(P0.z, S[ 2], r);
        r = fmaf(P0.w, S[34], r);
        r = fmaf(P1.x, S[35], r);
        r = fmaf(P1.y, S[36], r);
        r = fmaf(P1.z, S[68], r);
        r = fmaf(P1.w, S[69], r);
        r = fmaf(P2.x, S[70], r);
        float clp = fminf(fmaxf(r + 3.0f, 0.0f), 6.0f);
        float hs  = r * clp * (1.0f / 6.0f);

        // pointwise: 32 token FMAs (weights uniform)
        const float* wr = wtb + k * NT;
        v4f hv = {hs, hs, hs, hs};
        A0 = __builtin_elementwise_fma(hv, *(const v4f*)(wr +  0), A0);
        A1 = __builtin_elementwise_fma(hv, *(const v4f*)(wr +  4), A1);
        A2 = __builtin_elementwise_fma(hv, *(const v4f*)(wr +  8), A2);
        A3 = __builtin_elementwise_fma(hv, *(const v4f*)(wr + 12), A3);
        A4 = __builtin_elementwise_fma(hv, *(const v4f*)(wr + 16), A4);
        A5 = __builtin_elementwise_fma(hv, *(const v4f*)(wr + 20), A5);
        A6 = __builtin_elementwise_fma(hv, *(const v4f*)(wr + 24), A6);
        A7 = __builtin_elementwise_fma(hv, *(const v4f*)(wr + 28), A7);

        // late BN + LDS write of channel k+1 (loaded 2 iters ago)
        if (k + 1 < CHPB) {
            float sc = pkb[(k + 1) * 12 + 10], sh = pkb[(k + 1) * 12 + 11];
            float* Sn = &st[(k & 1) ^ 1][0];
            if (va) Sn[tid] = fmaf(g1a, sc, sh);
            if (vb) Sn[i1]  = fmaf(g1b, sc, sh);
        }
        g1a = g2a; g1b = g2b; g2a = g3a; g2b = g3b;
        __syncthreads();
    }

    float* po = partials + ((size_t)(scc * BATCH + b) * NT) * HWSZ
              + blockIdx.x * 256 + tid;
    po[ 0 << 10] = A0.x; po[ 1 << 10] = A0.y; po[ 2 << 10] = A0.z; po[ 3 << 10] = A0.w;
    po[ 4 << 10] = A1.x; po[ 5 << 10] = A1.y; po[ 6 << 10] = A1.z; po[ 7 << 10] = A1.w;
    po[ 8 << 10] = A2.x; po[ 9 << 10] = A2.y; po[10 << 10] = A2.z; po[11 << 10] = A2.w;
    po[12 << 10] = A3.x; po[13 << 10] = A3.y; po[14 << 10] = A3.z; po[15 << 10] = A3.w;
    po[16 << 10] = A4.x; po[17 << 10] = A4.y; po[18 << 10] = A4.z; po[19 << 10] = A4.w;
    po[20 << 10] = A5.x; po[21 << 10] = A5.y; po[22 << 10] = A5.z; po[23 << 10] = A5.w;
    po[24 << 10] = A6.x; po[25 << 10] = A6.y; po[26 << 10] = A6.z; po[27 << 10] = A6.w;
    po[28 << 10] = A7.x; po[29 << 10] = A7.y; po[30 << 10] = A7.z; po[31 << 10] = A7.w;
}

// ---------------- K3: sum partials -> argmax mask -> gather-sum ------------
template<int SCHT>
__global__ __launch_bounds__(256) void k3_mask_gather(
    const float* __restrict__ partials,
    const float* __restrict__ x, const float* __restrict__ posin,
    const float* __restrict__ bnw, const float* __restrict__ bnb,
    const float* __restrict__ bnm, const float* __restrict__ bnv,
    float* __restrict__ out)
{
    int bt = blockIdx.x;           // b*32 + t
    int b  = bt >> 5;
    int t  = bt & 31;
    int tid = threadIdx.x;

    const float4* pp4 = (const float4*)(partials + ((size_t)(b * NT) + t) * HWSZ) + tid;
    float4 acc = make_float4(0.f, 0.f, 0.f, 0.f);
#pragma unroll
    for (int s = 0; s < SCHT; ++s) {
        float4 u = pp4[(size_t)s * (BATCH * NT * HWSZ / 4)];
        acc.x += u.x; acc.y += u.y; acc.z += u.z; acc.w += u.w;
    }

    float m = fmaxf(fmaxf(acc.x, acc.y), fmaxf(acc.z, acc.w));
#pragma unroll
    for (int off = 32; off; off >>= 1)
        m = fmaxf(m, __shfl_xor(m, off));
    __shared__ float wm[4];
    if ((tid & 63) == 0) wm[tid >> 6] = m;
    __syncthreads();
    m = fmaxf(fmaxf(wm[0], wm[1]), fmaxf(wm[2], wm[3]));

    __shared__ int nmatch;
    __shared__ int matchpos[16];
    if (tid == 0) nmatch = 0;
    __syncthreads();

    float* maskp = out + OUT_MASK_OFF + (size_t)bt * HWSZ;
    float4 mask4;
    const float* av = &acc.x;
    float* mv = &mask4.x;
#pragma unroll
    for (int j = 0; j < 4; ++j) {
        int hit = (av[j] == m);
        mv[j] = hit ? 1.0f : 0.0f;
        if (hit) {
            int k = atomicAdd(&nmatch, 1);
            if (k < 16) matchpos[k] = 4 * tid + j;
        }
    }
    ((float4*)maskp)[tid] = mask4;
    __syncthreads();
    int nm = nmatch < 16 ? nmatch : 16;

    const float* xb = x + (size_t)b * DIMC * HWSZ;
    const float* pb = posin + (size_t)b * DIMC * HWSZ;
    for (int c = tid; c < DIMC; c += 256) {
        float scale = bnw[c] * rsqrtf(bnv[c] + 1e-5f);
        float shift = bnb[c] - bnm[c] * scale;
        float rf = 0.0f, rp = 0.0f;
        for (int k = 0; k < nm; ++k) {
            int pos = matchpos[k];
            rf += xb[(size_t)c * HWSZ + pos] * scale + shift;
            rp += pb[(size_t)c * HWSZ + pos];
        }
        out[(size_t)bt * DIMC + c] = rf;
        out[OUT_P_OFF + (size_t)bt * DIMC + c] = rp;
    }
}

extern "C" void kernel_launch(void* const* d_in, const int* in_sizes, int n_in,
                              void* d_out, int out_size, void* d_ws, size_t ws_size,
                              hipStream_t stream)
{
    const float* x    = (const float*)d_in[0];
    const float* pos  = (const float*)d_in[1];
    const float* bnw  = (const float*)d_in[2];
    const float* bnb  = (const float*)d_in[3];
    const float* bnm  = (const float*)d_in[4];
    const float* bnv  = (const float*)d_in[5];
    const float* dww  = (const float*)d_in[6];
    const float* dwb  = (const float*)d_in[7];
    const float* pww  = (const float*)d_in[8];
    // d_in[9] (pw_bias) unused: constant per (b,t) row -> outputs invariant.
    float* out = (float*)d_out;

    // choose SCH=32 (better occupancy) when workspace allows, else 16
    const size_t part32 = (size_t)32 * BATCH * NT * HWSZ;   // floats
    const size_t need32 = (part32 + 24576 + 9216) * sizeof(float);
    const bool big = ws_size >= need32;
    const size_t partN = (big ? (size_t)32 : (size_t)16) * BATCH * NT * HWSZ;

    float* partials = (float*)d_ws;
    float* wt       = (float*)d_ws + partN;
    float* pk       = wt + 24576;

    k0_prep<<<99, 256, 0, stream>>>(pww, dww, dwb, bnw, bnb, bnm, bnv, wt, pk);
    if (big) {
        kf_fused<24><<<dim3(4, 32, BATCH), 256, 0, stream>>>(x, wt, pk, partials);
        k3_mask_gather<32><<<BATCH * NT, 256, 0, stream>>>(partials, x, pos,
                                                           bnw, bnb, bnm, bnv, out);
    } else {
        kf_fused<48><<<dim3(4, 16, BATCH), 256, 0, stream>>>(x, wt, pk, partials);
        k3_mask_gather<16><<<BATCH * NT, 256, 0, stream>>>(partials, x, pos,
                                                           bnw, bnb, bnm, bnv, out);
    }
}